// Round 15
// baseline (158.457 us; speedup 1.0000x reference)
//
#include <hip/hip_runtime.h>
#include <hip/hip_bf16.h>
#include <stdint.h>

using f32x4  = __attribute__((ext_vector_type(4))) float;
using f32x16 = __attribute__((ext_vector_type(16))) float;
using bf16x8 = __attribute__((ext_vector_type(8))) short;

constexpr int BATCH = 4;
constexpr int LQ_   = 256;
constexpr int LK_   = 50000;
constexpr int OUTD  = 256;
constexpr int EIN   = 128;
constexpr int TR    = 32;                      // k-rows per tile
constexpr int NTC   = (LK_ + TR - 1) / TR;     // 1563 (tail tile short)
constexpr int KCH   = 128;                     // k-chunks per batch (grid 512 = 2/CU)

__device__ __forceinline__ uint32_t f2bf(float f) {
  uint32_t u = __builtin_bit_cast(uint32_t, f);
  u = (u + 0x7fffu + ((u >> 16) & 1u)) >> 16;
  return u;
}
__device__ __forceinline__ uint32_t cvtpk(float lo, float hi) {
  uint32_t r;
  asm volatile("v_cvt_pk_bf16_f32 %0, %1, %2" : "=v"(r) : "v"(lo), "v"(hi));
  return r;
}

// LDS-only barrier: drains this wave's LDS ops, raw s_barrier, no vmcnt drain.
__device__ __forceinline__ void block_sync_lds() {
  asm volatile("s_waitcnt lgkmcnt(0)" ::: "memory");
  __builtin_amdgcn_sched_barrier(0);
  __builtin_amdgcn_s_barrier();
  __builtin_amdgcn_sched_barrier(0);
}

// ---- prep_all: blocks 0-63 -> Gn, 64-95 -> cast Wv, 96 -> zero num/den ----
__global__ __launch_bounds__(256) void prep_all(
    const float* __restrict__ query, const float* __restrict__ Wq,
    const float* __restrict__ bq,    const float* __restrict__ Wk,
    const float* __restrict__ Wv,    ushort* __restrict__ Gn,
    ushort* __restrict__ Wvbf,       float* __restrict__ numden)
{
  const int blk = blockIdx.x, tid = threadIdx.x;
  if (blk >= 64) {
    if (blk < 96) {                       // cast Wv -> bf16 (32 blocks x 2048)
      int base = (blk - 64) * 2048 + tid * 8;
      float4 a = *(const float4*)(Wv + base);
      float4 c = *(const float4*)(Wv + base + 4);
      uint4 pk;
      pk.x = f2bf(a.x) | (f2bf(a.y) << 16);
      pk.y = f2bf(a.z) | (f2bf(a.w) << 16);
      pk.z = f2bf(c.x) | (f2bf(c.y) << 16);
      pk.w = f2bf(c.z) | (f2bf(c.w) << 16);
      *(uint4*)(Wvbf + base) = pk;
    } else {                              // zero the atomic accumulators
      for (int i = tid; i < 2 * BATCH * OUTD; i += 256) numden[i] = 0.f;
    }
    return;
  }
  // ---- Gn[b] = (1/16)*(query[b]@Wq^T + bq)@Wk, 16 q-rows per block -------
  __shared__ float qin[16 * EIN];
  __shared__ float Qr [16 * OUTD];
  const int b = blk >> 4, q0 = (blk & 15) * 16;
  {
    int idx = tid * 8;
    int row = idx >> 7, c = idx & 127;
    const float* p = query + ((size_t)b * LQ_ + q0 + row) * EIN + c;
    float4 a = *(const float4*)p;
    float4 d = *(const float4*)(p + 4);
    float* q = &qin[row * EIN + c];
    q[0]=a.x; q[1]=a.y; q[2]=a.z; q[3]=a.w; q[4]=d.x; q[5]=d.y; q[6]=d.z; q[7]=d.w;
  }
  __syncthreads();

  float acc[16];
  {
    float bias = bq[tid];
#pragma unroll
    for (int i = 0; i < 16; ++i) acc[i] = bias;
  }
  for (int d4 = 0; d4 < EIN / 4; ++d4) {
    f32x4 w4 = *(const f32x4*)(Wq + tid * EIN + d4 * 4);
#pragma unroll
    for (int i = 0; i < 16; ++i) {
      f32x4 q4 = *(const f32x4*)(qin + i * EIN + d4 * 4);
      acc[i] += q4[0]*w4[0] + q4[1]*w4[1] + q4[2]*w4[2] + q4[3]*w4[3];
    }
  }
#pragma unroll
  for (int i = 0; i < 16; ++i) Qr[i * OUTD + tid] = acc[i];
  __syncthreads();

  float acc2[16];
#pragma unroll
  for (int i = 0; i < 16; ++i) acc2[i] = 0.f;
  for (int d4 = 0; d4 < OUTD / 4; ++d4) {
    float w0 = Wk[(d4*4+0) * OUTD + tid];
    float w1 = Wk[(d4*4+1) * OUTD + tid];
    float w2 = Wk[(d4*4+2) * OUTD + tid];
    float w3 = Wk[(d4*4+3) * OUTD + tid];
#pragma unroll
    for (int i = 0; i < 16; ++i) {
      f32x4 q4 = *(const f32x4*)(Qr + i * OUTD + d4 * 4);
      acc2[i] += q4[0]*w0 + q4[1]*w1 + q4[2]*w2 + q4[3]*w3;
    }
  }
  const float norm = 0.0625f;
#pragma unroll
  for (int i = 0; i < 16; ++i)
    Gn[((size_t)b * LQ_ + q0 + i) * OUTD + tid] = (ushort)f2bf(acc2[i] * norm);
}

// ---- main ------------------------------------------------------------------
// 512 blocks (2/CU), 512 thr = 8 waves; wave w owns q-rows [w*32, w*32+32)
// via 32x32x16 MFMA -> 8x32 = all 256 q; block = (b, k-chunk), input read
// once. LDS-READ REDUNDANCY HALVED vs R11/R14: a B-frag K-step covers all 32
// k-rows, so 8 waves x 16 reads per 32-row tile (R14: 16 waves x 16).
// A-frags = 128 VGPR (ga[16]+wa[16]), asm-pinned; need ~228 < cap 256 from
// launch_bounds(512,2) -> first-ever test of pin WITH headroom at Mq=32
// (R4/R7 no-pin: demoted; R6 pin need>cap: spilled; R11 pin+headroom: OK).
// 2 blocks/CU keeps 16 waves/CU and de-correlates barrier domains.
// LDS: 2 x 16 KB, granule (fb 0..31, row 0..31) at fb*512 + ((row^fb)<<4);
// B-read lanes 0..31 span one fb XOR-permuted -> conflict-free; same family
// as R11-R14 (measured 0 conflicts). R11 cadence, lgkm-only barrier.
__global__ __launch_bounds__(512, 2) void attn_main(
    const float*  __restrict__ input, const ushort* __restrict__ Gn,
    const ushort* __restrict__ Wvbf,  float* __restrict__ num,
    float* __restrict__ den)
{
  __shared__ ushort in_lds[2 * 8192]; // 2 x 16 KB
  const int idx = blockIdx.x;
  const int b = idx >> 7, kch = idx & (KCH - 1);
  const int t0 = (kch * NTC) >> 7, t1 = ((kch + 1) * NTC) >> 7;
  const int tid = threadIdx.x, w = tid >> 6, l = tid & 63;
  const int hi = l >> 5, lk = l & 31;     // hi: k-feature half, lk: k-row/q-col
  const float* src = input + (size_t)b * LK_ * 256;

  // A-frags (32x32x16): q-row = w*32+lk, features ks*16 + hi*8 + [0,8)
  const int arow = w * 32 + lk;
  const ushort* gp = Gn   + ((size_t)b * LQ_ + arow) * 256 + hi * 8;
  const ushort* vp = Wvbf + (size_t)arow * 256 + hi * 8;
  bf16x8 ga[16], wa[16];
#pragma unroll
  for (int k = 0; k < 16; ++k) {
    ga[k] = *(const bf16x8*)(gp + k * 16);
    wa[k] = *(const bf16x8*)(vp + k * 16);
    asm volatile("" : "+v"(ga[k]), "+v"(wa[k]));  // forbid remat/sink
  }

  float numr[16], denr[16];
#pragma unroll
  for (int r = 0; r < 16; ++r) { numr[r] = 0.f; denr[r] = 0.f; }

  // staging: 2 granules/thread: g = i*512+tid -> row = g>>5 (0..31), fb = g&31
  const int g0row = tid >> 5, g0fb = tid & 31;      // i=0 granule
  float4 sa0, sa1, sb0, sb1;
  auto loadreg = [&](int t) {
    int r0 = t * TR + g0row;
    r0 = r0 < LK_ ? r0 : LK_ - 1;        // clamp (tail + prefetch overrun)
    const float* p0 = src + (size_t)r0 * 256 + g0fb * 8;
    sa0 = *(const float4*)p0;
    sa1 = *(const float4*)(p0 + 4);
    int r1 = t * TR + 16 + g0row;        // i=1: row += 16 (512/32)
    r1 = r1 < LK_ ? r1 : LK_ - 1;
    const float* p1 = src + (size_t)r1 * 256 + g0fb * 8;
    sb0 = *(const float4*)p1;
    sb1 = *(const float4*)(p1 + 4);
  };
  const int sw0 = g0fb * 512 + (((g0row +  0) ^ g0fb) << 4);
  const int sw1 = g0fb * 512 + (((g0row + 16) ^ g0fb) << 4);
  auto writebuf = [&](int buf) {
    char* base = (char*)in_lds + buf * 16384;
    uint4 pk;
    pk.x = cvtpk(sa0.x, sa0.y); pk.y = cvtpk(sa0.z, sa0.w);
    pk.z = cvtpk(sa1.x, sa1.y); pk.w = cvtpk(sa1.z, sa1.w);
    *(uint4*)(base + sw0) = pk;
    pk.x = cvtpk(sb0.x, sb0.y); pk.y = cvtpk(sb0.z, sb0.w);
    pk.z = cvtpk(sb1.x, sb1.y); pk.w = cvtpk(sb1.z, sb1.w);
    *(uint4*)(base + sw1) = pk;
  };

  loadreg(t0);
  writebuf(t0 & 1);
  loadreg(t0 + 1);                  // in flight across the barrier
  block_sync_lds();

  const bool tailc = (t1 == NTC);   // last chunk owns the ragged edge
  for (int t = t0; t < t1; ++t) {
    // ---- compute(t) from buf[t&1] ----
    const char* bbuf = (const char*)in_lds + (t & 1) * 16384;
    f32x16 aS = {0,0,0,0,0,0,0,0,0,0,0,0,0,0,0,0};
    f32x16 aV = {0,0,0,0,0,0,0,0,0,0,0,0,0,0,0,0};
#pragma unroll
    for (int ks = 0; ks < 16; ++ks) {
      const int fb = ks * 2 + hi;
      bf16x8 bb = *(const bf16x8*)(bbuf + fb * 512 + ((lk ^ fb) << 4));
      aS = __builtin_amdgcn_mfma_f32_32x32x16_bf16(ga[ks], bb, aS, 0, 0, 0);
      aV = __builtin_amdgcn_mfma_f32_32x32x16_bf16(wa[ks], bb, aV, 0, 0, 0);
    }
    {
      const bool valid = !tailc || (t * TR + lk) < LK_;
#pragma unroll
      for (int r = 0; r < 16; ++r) {
        float e = valid ? __expf(aS[r]) : 0.f;
        denr[r] += e;
        numr[r] += e * aV[r];
      }
    }
    // ---- stage: regs(t+1) -> buf[(t+1)&1]; issue loads(t+2) ----
    if (t + 1 < t1) {
      writebuf((t + 1) & 1);        // vmcnt-dep only on loads issued last iter
      if (t + 2 < t1) loadreg(t + 2);
    }
    block_sync_lds();               // single lgkm-only barrier per iter
  }

  // reduce over the 32 k-columns (lanes lk), one atomic per (q, {num,den})
#pragma unroll
  for (int r = 0; r < 16; ++r) {
    float d_ = denr[r], n_ = numr[r];
#pragma unroll
    for (int m = 1; m < 32; m <<= 1) {
      d_ += __shfl_xor(d_, m, 64);
      n_ += __shfl_xor(n_, m, 64);
    }
    if (lk == 0) {
      int q = w * 32 + (r & 3) + 8 * (r >> 2) + 4 * hi;  // 32x32 D-layout
      atomicAdd(&den[b * OUTD + q], d_);
      atomicAdd(&num[b * OUTD + q], n_);
    }
  }
}

// ---- finalize: out = num/den + bv ------------------------------------------
__global__ __launch_bounds__(256) void finalize(const float* __restrict__ num,
                                                const float* __restrict__ den,
                                                const float* __restrict__ bv,
                                                float* __restrict__ out) {
  int i = blockIdx.x * 256 + threadIdx.x;
  out[i] = num[i] / den[i] + bv[i & 255];
}

extern "C" void kernel_launch(void* const* d_in, const int* in_sizes, int n_in,
                              void* d_out, int out_size, void* d_ws, size_t ws_size,
                              hipStream_t stream)
{
  const float* query = (const float*)d_in[0];
  const float* input = (const float*)d_in[1];
  const float* Wq    = (const float*)d_in[2];
  const float* bq    = (const float*)d_in[3];
  const float* Wk    = (const float*)d_in[4];
  // d_in[5] = bk : softmax-invariant, unused
  const float* Wv    = (const float*)d_in[6];
  const float* bv    = (const float*)d_in[7];
  float* out = (float*)d_out;

  char* ws = (char*)d_ws;
  ushort* Gn     = (ushort*)ws;                       // 512 KB
  ushort* Wvbf   = (ushort*)(ws + 524288);            // 128 KB
  float*  numden = (float*)(ws + 524288 + 131072);    // 8 KB
  float*  num    = numden;
  float*  den    = numden + BATCH * OUTD;

  prep_all<<<97, 256, 0, stream>>>(query, Wq, bq, Wk, Wv, Gn, Wvbf, numden);
  attn_main<<<BATCH * KCH, 512, 0, stream>>>(input, Gn, Wvbf, num, den);
  finalize<<<BATCH, 256, 0, stream>>>(num, den, bv, out);
}

// Round 16
// 115.939 us; speedup vs baseline: 1.3667x; 1.3667x over previous
//
#include <hip/hip_runtime.h>
#include <hip/hip_bf16.h>
#include <stdint.h>

using f32x4  = __attribute__((ext_vector_type(4))) float;
using f32x16 = __attribute__((ext_vector_type(16))) float;
using bf16x8 = __attribute__((ext_vector_type(8))) short;

constexpr int BATCH = 4;
constexpr int LQ_   = 256;
constexpr int LK_   = 50000;
constexpr int OUTD  = 256;
constexpr int EIN   = 128;
constexpr int TR    = 32;                      // k-rows per tile
constexpr int NTC   = (LK_ + TR - 1) / TR;     // 1563 (tail tile short)
constexpr int KCH   = 64;                      // k-chunks per batch (grid 256 = 1/CU)

__device__ __forceinline__ uint32_t f2bf(float f) {
  uint32_t u = __builtin_bit_cast(uint32_t, f);
  u = (u + 0x7fffu + ((u >> 16) & 1u)) >> 16;
  return u;
}
__device__ __forceinline__ uint32_t cvtpk(float lo, float hi) {
  uint32_t r;
  asm volatile("v_cvt_pk_bf16_f32 %0, %1, %2" : "=v"(r) : "v"(lo), "v"(hi));
  return r;
}

// LDS-only barrier: drains this wave's LDS ops, raw s_barrier, no vmcnt drain.
__device__ __forceinline__ void block_sync_lds() {
  asm volatile("s_waitcnt lgkmcnt(0)" ::: "memory");
  __builtin_amdgcn_sched_barrier(0);
  __builtin_amdgcn_s_barrier();
  __builtin_amdgcn_sched_barrier(0);
}

// ---- prep_all: blocks 0-63 -> Gn, 64-95 -> cast Wv, 96 -> zero num/den ----
__global__ __launch_bounds__(256) void prep_all(
    const float* __restrict__ query, const float* __restrict__ Wq,
    const float* __restrict__ bq,    const float* __restrict__ Wk,
    const float* __restrict__ Wv,    ushort* __restrict__ Gn,
    ushort* __restrict__ Wvbf,       float* __restrict__ numden)
{
  const int blk = blockIdx.x, tid = threadIdx.x;
  if (blk >= 64) {
    if (blk < 96) {                       // cast Wv -> bf16 (32 blocks x 2048)
      int base = (blk - 64) * 2048 + tid * 8;
      float4 a = *(const float4*)(Wv + base);
      float4 c = *(const float4*)(Wv + base + 4);
      uint4 pk;
      pk.x = f2bf(a.x) | (f2bf(a.y) << 16);
      pk.y = f2bf(a.z) | (f2bf(a.w) << 16);
      pk.z = f2bf(c.x) | (f2bf(c.y) << 16);
      pk.w = f2bf(c.z) | (f2bf(c.w) << 16);
      *(uint4*)(Wvbf + base) = pk;
    } else {                              // zero the atomic accumulators
      for (int i = tid; i < 2 * BATCH * OUTD; i += 256) numden[i] = 0.f;
    }
    return;
  }
  // ---- Gn[b] = (1/16)*(query[b]@Wq^T + bq)@Wk, 16 q-rows per block -------
  __shared__ float qin[16 * EIN];
  __shared__ float Qr [16 * OUTD];
  const int b = blk >> 4, q0 = (blk & 15) * 16;
  {
    int idx = tid * 8;
    int row = idx >> 7, c = idx & 127;
    const float* p = query + ((size_t)b * LQ_ + q0 + row) * EIN + c;
    float4 a = *(const float4*)p;
    float4 d = *(const float4*)(p + 4);
    float* q = &qin[row * EIN + c];
    q[0]=a.x; q[1]=a.y; q[2]=a.z; q[3]=a.w; q[4]=d.x; q[5]=d.y; q[6]=d.z; q[7]=d.w;
  }
  __syncthreads();

  float acc[16];
  {
    float bias = bq[tid];
#pragma unroll
    for (int i = 0; i < 16; ++i) acc[i] = bias;
  }
  for (int d4 = 0; d4 < EIN / 4; ++d4) {
    f32x4 w4 = *(const f32x4*)(Wq + tid * EIN + d4 * 4);
#pragma unroll
    for (int i = 0; i < 16; ++i) {
      f32x4 q4 = *(const f32x4*)(qin + i * EIN + d4 * 4);
      acc[i] += q4[0]*w4[0] + q4[1]*w4[1] + q4[2]*w4[2] + q4[3]*w4[3];
    }
  }
#pragma unroll
  for (int i = 0; i < 16; ++i) Qr[i * OUTD + tid] = acc[i];
  __syncthreads();

  float acc2[16];
#pragma unroll
  for (int i = 0; i < 16; ++i) acc2[i] = 0.f;
  for (int d4 = 0; d4 < OUTD / 4; ++d4) {
    float w0 = Wk[(d4*4+0) * OUTD + tid];
    float w1 = Wk[(d4*4+1) * OUTD + tid];
    float w2 = Wk[(d4*4+2) * OUTD + tid];
    float w3 = Wk[(d4*4+3) * OUTD + tid];
#pragma unroll
    for (int i = 0; i < 16; ++i) {
      f32x4 q4 = *(const f32x4*)(Qr + i * OUTD + d4 * 4);
      acc2[i] += q4[0]*w0 + q4[1]*w1 + q4[2]*w2 + q4[3]*w3;
    }
  }
  const float norm = 0.0625f;
#pragma unroll
  for (int i = 0; i < 16; ++i)
    Gn[((size_t)b * LQ_ + q0 + i) * OUTD + tid] = (ushort)f2bf(acc2[i] * norm);
}

// ---- main ------------------------------------------------------------------
// 256 blocks (1/CU), 512 thr = 8 waves; wave w owns q-rows [w*32,w*32+32) via
// 32x32x16 MFMA -> 8x32 = all 256 q, input read once. THE FIX (R15 post-
// mortem): __launch_bounds__'s 2nd arg is a MIN waves/EU -- the allocator may
// target MORE and clamp regs to 128, demoting the 128-reg A-frags to in-loop
// reloads (this killed R5-R8 and R15). amdgpu_waves_per_eu(2,2) pins the
// occupancy target to exactly 2 waves/SIMD -> true 256-reg budget -> ga/wa
// genuinely resident -> inner loop is pure {16 ds_read + 32 MFMA}, no global.
// LDS redundancy halved vs R11: 8 waves x 16KB per 32-row tile = 4KB/k-row.
// LDS: 2 x 16 KB, granule (fb 0..31, row 0..31) at fb*512 + ((row^fb)<<4)
// (write & read bank-uniform, measured 0 conflicts). R11 cadence: compute ->
// stage(t+1)+issue(t+2) -> single lgkm-only barrier (prefetch never drained).
__global__ __launch_bounds__(512)
__attribute__((amdgpu_waves_per_eu(2, 2)))
void attn_main(
    const float*  __restrict__ input, const ushort* __restrict__ Gn,
    const ushort* __restrict__ Wvbf,  float* __restrict__ num,
    float* __restrict__ den)
{
  __shared__ ushort in_lds[2 * 8192]; // 2 x 16 KB
  const int idx = blockIdx.x;
  const int b = idx >> 6, kch = idx & (KCH - 1);
  const int t0 = (kch * NTC) >> 6, t1 = ((kch + 1) * NTC) >> 6;
  const int tid = threadIdx.x, w = tid >> 6, l = tid & 63;
  const int hi = l >> 5, lk = l & 31;     // hi: k-feature half, lk: k-row/q-col
  const float* src = input + (size_t)b * LK_ * 256;

  // A-frags (32x32x16): q-row = w*32+lk, features ks*16 + hi*8 + [0,8)
  const int arow = w * 32 + lk;
  const ushort* gp = Gn   + ((size_t)b * LQ_ + arow) * 256 + hi * 8;
  const ushort* vp = Wvbf + (size_t)arow * 256 + hi * 8;
  bf16x8 ga[16], wa[16];
#pragma unroll
  for (int k = 0; k < 16; ++k) {
    ga[k] = *(const bf16x8*)(gp + k * 16);
    wa[k] = *(const bf16x8*)(vp + k * 16);
    asm volatile("" : "+v"(ga[k]), "+v"(wa[k]));  // forbid remat/sink
  }

  float numr[16], denr[16];
#pragma unroll
  for (int r = 0; r < 16; ++r) { numr[r] = 0.f; denr[r] = 0.f; }

  // staging: 2 granules/thread: g = i*512+tid -> row = g>>5 (0..31), fb = g&31
  const int g0row = tid >> 5, g0fb = tid & 31;      // i=0 granule
  float4 sa0, sa1, sb0, sb1;
  auto loadreg = [&](int t) {
    int r0 = t * TR + g0row;
    r0 = r0 < LK_ ? r0 : LK_ - 1;        // clamp (tail + prefetch overrun)
    const float* p0 = src + (size_t)r0 * 256 + g0fb * 8;
    sa0 = *(const float4*)p0;
    sa1 = *(const float4*)(p0 + 4);
    int r1 = t * TR + 16 + g0row;        // i=1: row += 16 (512/32)
    r1 = r1 < LK_ ? r1 : LK_ - 1;
    const float* p1 = src + (size_t)r1 * 256 + g0fb * 8;
    sb0 = *(const float4*)p1;
    sb1 = *(const float4*)(p1 + 4);
  };
  const int sw0 = g0fb * 512 + (((g0row +  0) ^ g0fb) << 4);
  const int sw1 = g0fb * 512 + (((g0row + 16) ^ g0fb) << 4);
  auto writebuf = [&](int buf) {
    char* base = (char*)in_lds + buf * 16384;
    uint4 pk;
    pk.x = cvtpk(sa0.x, sa0.y); pk.y = cvtpk(sa0.z, sa0.w);
    pk.z = cvtpk(sa1.x, sa1.y); pk.w = cvtpk(sa1.z, sa1.w);
    *(uint4*)(base + sw0) = pk;
    pk.x = cvtpk(sb0.x, sb0.y); pk.y = cvtpk(sb0.z, sb0.w);
    pk.z = cvtpk(sb1.x, sb1.y); pk.w = cvtpk(sb1.z, sb1.w);
    *(uint4*)(base + sw1) = pk;
  };

  loadreg(t0);
  writebuf(t0 & 1);
  loadreg(t0 + 1);                  // in flight across the barrier
  block_sync_lds();

  const bool tailc = (t1 == NTC);   // last chunk owns the ragged edge
  for (int t = t0; t < t1; ++t) {
    // ---- compute(t) from buf[t&1] ----
    const char* bbuf = (const char*)in_lds + (t & 1) * 16384;
    f32x16 aS = {0,0,0,0,0,0,0,0,0,0,0,0,0,0,0,0};
    f32x16 aV = {0,0,0,0,0,0,0,0,0,0,0,0,0,0,0,0};
#pragma unroll
    for (int ks = 0; ks < 16; ++ks) {
      const int fb = ks * 2 + hi;
      bf16x8 bb = *(const bf16x8*)(bbuf + fb * 512 + ((lk ^ fb) << 4));
      aS = __builtin_amdgcn_mfma_f32_32x32x16_bf16(ga[ks], bb, aS, 0, 0, 0);
      aV = __builtin_amdgcn_mfma_f32_32x32x16_bf16(wa[ks], bb, aV, 0, 0, 0);
    }
    {
      const bool valid = !tailc || (t * TR + lk) < LK_;
#pragma unroll
      for (int r = 0; r < 16; ++r) {
        float e = valid ? __expf(aS[r]) : 0.f;
        denr[r] += e;
        numr[r] += e * aV[r];
      }
    }
    // ---- stage: regs(t+1) -> buf[(t+1)&1]; issue loads(t+2) ----
    if (t + 1 < t1) {
      writebuf((t + 1) & 1);        // vmcnt-dep only on loads issued last iter
      if (t + 2 < t1) loadreg(t + 2);
    }
    block_sync_lds();               // single lgkm-only barrier per iter
  }

  // reduce over the 32 k-columns (lanes lk), one atomic per (q, {num,den})
#pragma unroll
  for (int r = 0; r < 16; ++r) {
    float d_ = denr[r], n_ = numr[r];
#pragma unroll
    for (int m = 1; m < 32; m <<= 1) {
      d_ += __shfl_xor(d_, m, 64);
      n_ += __shfl_xor(n_, m, 64);
    }
    if (lk == 0) {
      int q = w * 32 + (r & 3) + 8 * (r >> 2) + 4 * hi;  // 32x32 D-layout
      atomicAdd(&den[b * OUTD + q], d_);
      atomicAdd(&num[b * OUTD + q], n_);
    }
  }
}

// ---- finalize: out = num/den + bv ------------------------------------------
__global__ __launch_bounds__(256) void finalize(const float* __restrict__ num,
                                                const float* __restrict__ den,
                                                const float* __restrict__ bv,
                                                float* __restrict__ out) {
  int i = blockIdx.x * 256 + threadIdx.x;
  out[i] = num[i] / den[i] + bv[i & 255];
}

extern "C" void kernel_launch(void* const* d_in, const int* in_sizes, int n_in,
                              void* d_out, int out_size, void* d_ws, size_t ws_size,
                              hipStream_t stream)
{
  const float* query = (const float*)d_in[0];
  const float* input = (const float*)d_in[1];
  const float* Wq    = (const float*)d_in[2];
  const float* bq    = (const float*)d_in[3];
  const float* Wk    = (const float*)d_in[4];
  // d_in[5] = bk : softmax-invariant, unused
  const float* Wv    = (const float*)d_in[6];
  const float* bv    = (const float*)d_in[7];
  float* out = (float*)d_out;

  char* ws = (char*)d_ws;
  ushort* Gn     = (ushort*)ws;                       // 512 KB
  ushort* Wvbf   = (ushort*)(ws + 524288);            // 128 KB
  float*  numden = (float*)(ws + 524288 + 131072);    // 8 KB
  float*  num    = numden;
  float*  den    = numden + BATCH * OUTD;

  prep_all<<<97, 256, 0, stream>>>(query, Wq, bq, Wk, Wv, Gn, Wvbf, numden);
  attn_main<<<BATCH * KCH, 512, 0, stream>>>(input, Gn, Wvbf, num, den);
  finalize<<<BATCH, 256, 0, stream>>>(num, den, bv, out);
}

// Round 17
// 105.829 us; speedup vs baseline: 1.4973x; 1.0955x over previous
//
#include <hip/hip_runtime.h>
#include <hip/hip_bf16.h>
#include <stdint.h>

using f32x4  = __attribute__((ext_vector_type(4))) float;
using bf16x8 = __attribute__((ext_vector_type(8))) short;

constexpr int BATCH = 4;
constexpr int LQ_   = 256;
constexpr int LK_   = 50000;
constexpr int OUTD  = 256;
constexpr int EIN   = 128;
constexpr int TR    = 16;                      // k-rows per tile
constexpr int NT    = LK_ / TR;                // 3125 (exact)
constexpr int KCH   = 64;                      // k-chunks per batch (grid 256 = 1/CU)

__device__ __forceinline__ uint32_t f2bf(float f) {
  uint32_t u = __builtin_bit_cast(uint32_t, f);
  u = (u + 0x7fffu + ((u >> 16) & 1u)) >> 16;
  return u;
}

// LDS-only barrier: drains this wave's LDS ops, raw s_barrier, no vmcnt drain.
__device__ __forceinline__ void block_sync_lds() {
  asm volatile("s_waitcnt lgkmcnt(0)" ::: "memory");
  __builtin_amdgcn_sched_barrier(0);
  __builtin_amdgcn_s_barrier();
  __builtin_amdgcn_sched_barrier(0);
}

// ---- prep_all: blocks 0-63 -> Gn, 64-95 -> cast Wv, 96 -> zero num/den ----
__global__ __launch_bounds__(256) void prep_all(
    const float* __restrict__ query, const float* __restrict__ Wq,
    const float* __restrict__ bq,    const float* __restrict__ Wk,
    const float* __restrict__ Wv,    ushort* __restrict__ Gn,
    ushort* __restrict__ Wvbf,       float* __restrict__ numden)
{
  const int blk = blockIdx.x, tid = threadIdx.x;
  if (blk >= 64) {
    if (blk < 96) {                       // cast Wv -> bf16 (32 blocks x 2048)
      int base = (blk - 64) * 2048 + tid * 8;
      float4 a = *(const float4*)(Wv + base);
      float4 c = *(const float4*)(Wv + base + 4);
      uint4 pk;
      pk.x = f2bf(a.x) | (f2bf(a.y) << 16);
      pk.y = f2bf(a.z) | (f2bf(a.w) << 16);
      pk.z = f2bf(c.x) | (f2bf(c.y) << 16);
      pk.w = f2bf(c.z) | (f2bf(c.w) << 16);
      *(uint4*)(Wvbf + base) = pk;
    } else {                              // zero the atomic accumulators
      for (int i = tid; i < 2 * BATCH * OUTD; i += 256) numden[i] = 0.f;
    }
    return;
  }
  // ---- Gn[b] = (1/16)*(query[b]@Wq^T + bq)@Wk, 16 q-rows per block -------
  __shared__ float qin[16 * EIN];
  __shared__ float Qr [16 * OUTD];
  const int b = blk >> 4, q0 = (blk & 15) * 16;
  {
    int idx = tid * 8;
    int row = idx >> 7, c = idx & 127;
    const float* p = query + ((size_t)b * LQ_ + q0 + row) * EIN + c;
    float4 a = *(const float4*)p;
    float4 d = *(const float4*)(p + 4);
    float* q = &qin[row * EIN + c];
    q[0]=a.x; q[1]=a.y; q[2]=a.z; q[3]=a.w; q[4]=d.x; q[5]=d.y; q[6]=d.z; q[7]=d.w;
  }
  __syncthreads();

  float acc[16];
  {
    float bias = bq[tid];
#pragma unroll
    for (int i = 0; i < 16; ++i) acc[i] = bias;
  }
  for (int d4 = 0; d4 < EIN / 4; ++d4) {
    f32x4 w4 = *(const f32x4*)(Wq + tid * EIN + d4 * 4);
#pragma unroll
    for (int i = 0; i < 16; ++i) {
      f32x4 q4 = *(const f32x4*)(qin + i * EIN + d4 * 4);
      acc[i] += q4[0]*w4[0] + q4[1]*w4[1] + q4[2]*w4[2] + q4[3]*w4[3];
    }
  }
#pragma unroll
  for (int i = 0; i < 16; ++i) Qr[i * OUTD + tid] = acc[i];
  __syncthreads();

  float acc2[16];
#pragma unroll
  for (int i = 0; i < 16; ++i) acc2[i] = 0.f;
  for (int d4 = 0; d4 < OUTD / 4; ++d4) {
    float w0 = Wk[(d4*4+0) * OUTD + tid];
    float w1 = Wk[(d4*4+1) * OUTD + tid];
    float w2 = Wk[(d4*4+2) * OUTD + tid];
    float w3 = Wk[(d4*4+3) * OUTD + tid];
#pragma unroll
    for (int i = 0; i < 16; ++i) {
      f32x4 q4 = *(const f32x4*)(Qr + i * OUTD + d4 * 4);
      acc2[i] += q4[0]*w0 + q4[1]*w1 + q4[2]*w2 + q4[3]*w3;
    }
  }
  const float norm = 0.0625f;
#pragma unroll
  for (int i = 0; i < 16; ++i)
    Gn[((size_t)b * LQ_ + q0 + i) * OUTD + tid] = (ushort)f2bf(acc2[i] * norm);
}

// ---- main ------------------------------------------------------------------
// R11 config verbatim (best measured: 256 blocks = 1/CU, 1024 thr = 16 waves,
// wave w owns q-rows [w*16,w*16+16), 64-VGPR pinned A-frags, 2x8KB swizzled
// bf16 LDS dbuf, single lgkm-only barrier/iter) + ONE new instruction:
// sched_barrier(0) between writebuf(t+1) and loadreg(t+2). Without it the
// compiler may hoist the t+2 global loads above the t+1 ds_writes; vmcnt is
// an ORDERED counter, so the auto-wait before the ds_writes then covers the
// just-issued t+2 loads -> a full HBM round-trip on the critical path of
// EVERY iteration (invisible to all PMC pipes, insensitive to occupancy /
// prefetch depth / tile size -- matching R11-R16's flat ~267 cyc/k-row).
// The fence keeps issue order stage(t+1)-writes THEN t+2-loads: the waits
// cover only iteration-old loads (landed), t+2 still gets ~4000 cyc flight.
__global__ __launch_bounds__(1024, 4) void attn_main(
    const float*  __restrict__ input, const ushort* __restrict__ Gn,
    const ushort* __restrict__ Wvbf,  float* __restrict__ num,
    float* __restrict__ den)
{
  __shared__ ushort in_lds[2 * 4096]; // 2 x 8 KB
  const int idx = blockIdx.x;
  const int b = idx >> 6, kch = idx & (KCH - 1);
  const int t0 = (kch * NT) >> 6, t1 = ((kch + 1) * NT) >> 6;
  const int tid = threadIdx.x, w = tid >> 6, l = tid & 63;
  const int lg = l >> 4, lr = l & 15;     // lane-group (k-features) / row
  const float* src = input + (size_t)b * LK_ * 256;

  // A-frags (16x16x32): q-row = w*16+lr, features ks*32 + lg*8 + [0,8)
  const int arow = w * 16 + lr;
  const ushort* gp = Gn   + ((size_t)b * LQ_ + arow) * 256 + lg * 8;
  const ushort* vp = Wvbf + (size_t)arow * 256 + lg * 8;
  bf16x8 ga[8], wa[8];
#pragma unroll
  for (int k = 0; k < 8; ++k) {
    ga[k] = *(const bf16x8*)(gp + k * 32);
    wa[k] = *(const bf16x8*)(vp + k * 32);
    asm volatile("" : "+v"(ga[k]), "+v"(wa[k]));  // forbid remat/sink
  }

  float numr[4], denr[4];
#pragma unroll
  for (int r = 0; r < 4; ++r) { numr[r] = 0.f; denr[r] = 0.f; }

  // staging: thread = half-granule. g = tid>>1: row = g>>5 (0..15),
  // fbg = g&31 (0..31), h = tid&1 -> f32 cols fbg*8 + h*4 .. +4.
  const int sg = tid >> 1, sh = tid & 1;
  const int srow = sg >> 5, sfbg = sg & 31;
  float4 s0;
  auto loadreg = [&](int t) {
    const float* p = src + (size_t)(t * TR + srow) * 256 + sfbg * 8 + sh * 4;
    s0 = *(const float4*)p;
  };
  auto writebuf = [&](int buf) {
    char* base = (char*)in_lds + buf * 8192;
    uint2 pk;
    pk.x = f2bf(s0.x) | (f2bf(s0.y) << 16);
    pk.y = f2bf(s0.z) | (f2bf(s0.w) << 16);
    *(uint2*)(base + sfbg * 256 + ((srow ^ (sfbg & 15)) << 4) + sh * 8) = pk;
  };

  loadreg(t0);
  writebuf(t0 & 1);
  __builtin_amdgcn_sched_barrier(0);
  loadreg(t0 + 1);                  // in flight across the barrier
  block_sync_lds();

  for (int t = t0; t < t1; ++t) {
    // ---- compute(t) from buf[t&1] ----
    const char* bbuf = (const char*)in_lds + (t & 1) * 8192;
    f32x4 aS = {0,0,0,0};
    f32x4 aV = {0,0,0,0};
#pragma unroll
    for (int ks = 0; ks < 8; ++ks) {
      const int fb = ks * 4 + lg;
      bf16x8 bb = *(const bf16x8*)(bbuf + fb * 256 + ((lr ^ (fb & 15)) << 4));
      aS = __builtin_amdgcn_mfma_f32_16x16x32_bf16(ga[ks], bb, aS, 0, 0, 0);
      aV = __builtin_amdgcn_mfma_f32_16x16x32_bf16(wa[ks], bb, aV, 0, 0, 0);
    }
#pragma unroll
    for (int r = 0; r < 4; ++r) {
      float e = __expf(aS[r]);      // no mask: 16 | LK exactly
      denr[r] += e;
      numr[r] += e * aV[r];
    }
    // ---- stage: regs(t+1) -> buf[(t+1)&1]; THEN (fenced) issue loads(t+2)
    if (t + 1 < t1) {
      writebuf((t + 1) & 1);        // deps = loads issued LAST iter (landed)
      __builtin_amdgcn_sched_barrier(0);  // THE FIX: t+2 loads must not hoist
                                          // above these ds_writes (vmcnt order)
      if (t + 2 < t1) loadreg(t + 2);
    }
    block_sync_lds();               // single lgkm-only barrier per iter
  }

  // reduce over the 16 k-columns (lanes lr), one atomic per (q, {num,den})
#pragma unroll
  for (int r = 0; r < 4; ++r) {
    float d_ = denr[r], n_ = numr[r];
#pragma unroll
    for (int m = 1; m < 16; m <<= 1) {
      d_ += __shfl_xor(d_, m, 64);
      n_ += __shfl_xor(n_, m, 64);
    }
    if (lr == 0) {
      int q = w * 16 + lg * 4 + r;  // D row = (lane>>4)*4 + reg
      atomicAdd(&den[b * OUTD + q], d_);
      atomicAdd(&num[b * OUTD + q], n_);
    }
  }
}

// ---- finalize: out = num/den + bv ------------------------------------------
__global__ __launch_bounds__(256) void finalize(const float* __restrict__ num,
                                                const float* __restrict__ den,
                                                const float* __restrict__ bv,
                                                float* __restrict__ out) {
  int i = blockIdx.x * 256 + threadIdx.x;
  out[i] = num[i] / den[i] + bv[i & 255];
}

extern "C" void kernel_launch(void* const* d_in, const int* in_sizes, int n_in,
                              void* d_out, int out_size, void* d_ws, size_t ws_size,
                              hipStream_t stream)
{
  const float* query = (const float*)d_in[0];
  const float* input = (const float*)d_in[1];
  const float* Wq    = (const float*)d_in[2];
  const float* bq    = (const float*)d_in[3];
  const float* Wk    = (const float*)d_in[4];
  // d_in[5] = bk : softmax-invariant, unused
  const float* Wv    = (const float*)d_in[6];
  const float* bv    = (const float*)d_in[7];
  float* out = (float*)d_out;

  char* ws = (char*)d_ws;
  ushort* Gn     = (ushort*)ws;                       // 512 KB
  ushort* Wvbf   = (ushort*)(ws + 524288);            // 128 KB
  float*  numden = (float*)(ws + 524288 + 131072);    // 8 KB
  float*  num    = numden;
  float*  den    = numden + BATCH * OUTD;

  prep_all<<<97, 256, 0, stream>>>(query, Wq, bq, Wk, Wv, Gn, Wvbf, numden);
  attn_main<<<BATCH * KCH, 1024, 0, stream>>>(input, Gn, Wvbf, num, den);
  finalize<<<BATCH, 256, 0, stream>>>(num, den, bv, out);
}

// Round 18
// 98.546 us; speedup vs baseline: 1.6080x; 1.0739x over previous
//
#include <hip/hip_runtime.h>
#include <hip/hip_bf16.h>
#include <stdint.h>

using f32x4  = __attribute__((ext_vector_type(4))) float;
using bf16x8 = __attribute__((ext_vector_type(8))) short;

constexpr int BATCH = 4;
constexpr int LQ_   = 256;
constexpr int LK_   = 50000;
constexpr int OUTD  = 256;
constexpr int EIN   = 128;
constexpr int TR    = 16;                      // k-rows per tile
constexpr int NT    = LK_ / TR;                // 3125 (exact)
constexpr int KCH   = 64;                      // k-chunks per batch (grid 256 = 1/CU)

__device__ __forceinline__ uint32_t f2bf(float f) {
  uint32_t u = __builtin_bit_cast(uint32_t, f);
  u = (u + 0x7fffu + ((u >> 16) & 1u)) >> 16;
  return u;
}

// LDS-only barrier: drains this wave's LDS ops, raw s_barrier, no vmcnt drain.
__device__ __forceinline__ void block_sync_lds() {
  asm volatile("s_waitcnt lgkmcnt(0)" ::: "memory");
  __builtin_amdgcn_sched_barrier(0);
  __builtin_amdgcn_s_barrier();
  __builtin_amdgcn_sched_barrier(0);
}

// ---- prep1: blocks 0-63 -> Q = query@Wq^T + bq (f32, to ws);
//             blocks 64-95 -> cast Wv->bf16; block 96 -> zero num/den -------
__global__ __launch_bounds__(256) void prep1(
    const float* __restrict__ query, const float* __restrict__ Wq,
    const float* __restrict__ bq,    const float* __restrict__ Wv,
    float* __restrict__ Qws,         ushort* __restrict__ Wvbf,
    float* __restrict__ numden)
{
  const int blk = blockIdx.x, tid = threadIdx.x;
  if (blk >= 64) {
    if (blk < 96) {                       // cast Wv -> bf16 (32 blocks x 2048)
      int base = (blk - 64) * 2048 + tid * 8;
      float4 a = *(const float4*)(Wv + base);
      float4 c = *(const float4*)(Wv + base + 4);
      uint4 pk;
      pk.x = f2bf(a.x) | (f2bf(a.y) << 16);
      pk.y = f2bf(a.z) | (f2bf(a.w) << 16);
      pk.z = f2bf(c.x) | (f2bf(c.y) << 16);
      pk.w = f2bf(c.z) | (f2bf(c.w) << 16);
      *(uint4*)(Wvbf + base) = pk;
    } else {
      for (int i = tid; i < 2 * BATCH * OUTD; i += 256) numden[i] = 0.f;
    }
    return;
  }
  __shared__ float qin[16 * EIN];    // 8 KB
  const int b = blk >> 4, q0 = (blk & 15) * 16;
  {
    int idx = tid * 8;
    int row = idx >> 7, c = idx & 127;
    const float* p = query + ((size_t)b * LQ_ + q0 + row) * EIN + c;
    float4 a = *(const float4*)p;
    float4 d = *(const float4*)(p + 4);
    float* q = &qin[row * EIN + c];
    q[0]=a.x; q[1]=a.y; q[2]=a.z; q[3]=a.w; q[4]=d.x; q[5]=d.y; q[6]=d.z; q[7]=d.w;
  }
  __syncthreads();

  float acc[16];
  {
    float bias = bq[tid];
#pragma unroll
    for (int i = 0; i < 16; ++i) acc[i] = bias;
  }
  for (int d4 = 0; d4 < EIN / 4; ++d4) {
    f32x4 w4 = *(const f32x4*)(Wq + tid * EIN + d4 * 4);
#pragma unroll
    for (int i = 0; i < 16; ++i) {
      f32x4 q4 = *(const f32x4*)(qin + i * EIN + d4 * 4);
      acc[i] += q4[0]*w4[0] + q4[1]*w4[1] + q4[2]*w4[2] + q4[3]*w4[3];
    }
  }
#pragma unroll
  for (int i = 0; i < 16; ++i)
    Qws[((size_t)b * LQ_ + q0 + i) * OUTD + tid] = acc[i];
}

// ---- prep2: Gn = (log2e/16) * Q @ Wk  -> bf16. 256 blocks, 4x parallel ----
// block = (b, q16, colg): b = blk>>6, q0 = ((blk>>2)&15)*16, colg = blk&3.
__global__ __launch_bounds__(256) void prep2(
    const float* __restrict__ Qws, const float* __restrict__ Wk,
    ushort* __restrict__ Gn)
{
  __shared__ float Qr[16 * OUTD];    // 16 KB
  const int blk = blockIdx.x, tid = threadIdx.x;
  const int b = blk >> 6, q0 = ((blk >> 2) & 15) * 16, colg = blk & 3;
  {  // stage Q rows [q0, q0+16) fully (all 256 cols)
    int idx = tid * 16;
    int row = idx >> 8, c = idx & 255;
    const float* p = Qws + ((size_t)b * LQ_ + q0 + row) * OUTD + c;
    float4* q = (float4*)&Qr[row * OUTD + c];
    q[0] = *(const float4*)p;
    q[1] = *(const float4*)(p + 4);
    q[2] = *(const float4*)(p + 8);
    q[3] = *(const float4*)(p + 12);
  }
  __syncthreads();

  // thread -> (col = colg*64 + tid&63, rows rg*4 .. rg*4+4) of 16
  const int col = colg * 64 + (tid & 63), rg = tid >> 6;
  float acc[4] = {0.f, 0.f, 0.f, 0.f};
  for (int d = 0; d < OUTD; ++d) {
    float wv = Wk[d * OUTD + col];
#pragma unroll
    for (int i = 0; i < 4; ++i) acc[i] += Qr[(rg * 4 + i) * OUTD + d] * wv;
  }
  const float nrm = 1.4426950408889634f * 0.0625f;  // log2(e)/sqrt(256)
#pragma unroll
  for (int i = 0; i < 4; ++i)
    Gn[((size_t)b * LQ_ + q0 + rg * 4 + i) * OUTD + col] = (ushort)f2bf(acc[i] * nrm);
}

// ---- main: R11 verbatim + exp2 (log2e folded into Gn) ----------------------
// 256 blocks (1/CU), 1024 thr = 16 waves; wave w owns q-rows [w*16,w*16+16).
// A-frags 64 VGPR pinned; 2x8KB swizzled bf16 LDS dbuf; reg-staged coalesced
// loads; single lgkm-only barrier/iter; prefetch one tile ahead. Scores come
// out of MFMA pre-scaled by log2e -> e = exp2f(S') = bare v_exp_f32 (softmax
// invariant under exponent-base change).
__global__ __launch_bounds__(1024, 4) void attn_main(
    const float*  __restrict__ input, const ushort* __restrict__ Gn,
    const ushort* __restrict__ Wvbf,  float* __restrict__ num,
    float* __restrict__ den)
{
  __shared__ ushort in_lds[2 * 4096]; // 2 x 8 KB
  const int idx = blockIdx.x;
  const int b = idx >> 6, kch = idx & (KCH - 1);
  const int t0 = (kch * NT) >> 6, t1 = ((kch + 1) * NT) >> 6;
  const int tid = threadIdx.x, w = tid >> 6, l = tid & 63;
  const int lg = l >> 4, lr = l & 15;
  const float* src = input + (size_t)b * LK_ * 256;

  const int arow = w * 16 + lr;
  const ushort* gp = Gn   + ((size_t)b * LQ_ + arow) * 256 + lg * 8;
  const ushort* vp = Wvbf + (size_t)arow * 256 + lg * 8;
  bf16x8 ga[8], wa[8];
#pragma unroll
  for (int k = 0; k < 8; ++k) {
    ga[k] = *(const bf16x8*)(gp + k * 32);
    wa[k] = *(const bf16x8*)(vp + k * 32);
    asm volatile("" : "+v"(ga[k]), "+v"(wa[k]));  // forbid remat/sink
  }

  float numr[4], denr[4];
#pragma unroll
  for (int r = 0; r < 4; ++r) { numr[r] = 0.f; denr[r] = 0.f; }

  const int sg = tid >> 1, sh = tid & 1;
  const int srow = sg >> 5, sfbg = sg & 31;
  float4 s0;
  auto loadreg = [&](int t) {
    const float* p = src + (size_t)(t * TR + srow) * 256 + sfbg * 8 + sh * 4;
    s0 = *(const float4*)p;
  };
  auto writebuf = [&](int buf) {
    char* base = (char*)in_lds + buf * 8192;
    uint2 pk;
    pk.x = f2bf(s0.x) | (f2bf(s0.y) << 16);
    pk.y = f2bf(s0.z) | (f2bf(s0.w) << 16);
    *(uint2*)(base + sfbg * 256 + ((srow ^ (sfbg & 15)) << 4) + sh * 8) = pk;
  };

  loadreg(t0);
  writebuf(t0 & 1);
  loadreg(t0 + 1);
  block_sync_lds();

  for (int t = t0; t < t1; ++t) {
    const char* bbuf = (const char*)in_lds + (t & 1) * 8192;
    f32x4 aS = {0,0,0,0};
    f32x4 aV = {0,0,0,0};
#pragma unroll
    for (int ks = 0; ks < 8; ++ks) {
      const int fb = ks * 4 + lg;
      bf16x8 bb = *(const bf16x8*)(bbuf + fb * 256 + ((lr ^ (fb & 15)) << 4));
      aS = __builtin_amdgcn_mfma_f32_16x16x32_bf16(ga[ks], bb, aS, 0, 0, 0);
      aV = __builtin_amdgcn_mfma_f32_16x16x32_bf16(wa[ks], bb, aV, 0, 0, 0);
    }
#pragma unroll
    for (int r = 0; r < 4; ++r) {
      float e = exp2f(aS[r]);       // bare v_exp_f32 (log2e pre-folded)
      denr[r] += e;
      numr[r] += e * aV[r];
    }
    if (t + 1 < t1) {
      writebuf((t + 1) & 1);
      if (t + 2 < t1) loadreg(t + 2);
    }
    block_sync_lds();
  }

#pragma unroll
  for (int r = 0; r < 4; ++r) {
    float d_ = denr[r], n_ = numr[r];
#pragma unroll
    for (int m = 1; m < 16; m <<= 1) {
      d_ += __shfl_xor(d_, m, 64);
      n_ += __shfl_xor(n_, m, 64);
    }
    if (lr == 0) {
      int q = w * 16 + lg * 4 + r;
      atomicAdd(&den[b * OUTD + q], d_);
      atomicAdd(&num[b * OUTD + q], n_);
    }
  }
}

// ---- finalize: out = num/den + bv ------------------------------------------
__global__ __launch_bounds__(256) void finalize(const float* __restrict__ num,
                                                const float* __restrict__ den,
                                                const float* __restrict__ bv,
                                                float* __restrict__ out) {
  int i = blockIdx.x * 256 + threadIdx.x;
  out[i] = num[i] / den[i] + bv[i & 255];
}

extern "C" void kernel_launch(void* const* d_in, const int* in_sizes, int n_in,
                              void* d_out, int out_size, void* d_ws, size_t ws_size,
                              hipStream_t stream)
{
  const float* query = (const float*)d_in[0];
  const float* input = (const float*)d_in[1];
  const float* Wq    = (const float*)d_in[2];
  const float* bq    = (const float*)d_in[3];
  const float* Wk    = (const float*)d_in[4];
  // d_in[5] = bk : softmax-invariant, unused
  const float* Wv    = (const float*)d_in[6];
  const float* bv    = (const float*)d_in[7];
  float* out = (float*)d_out;

  char* ws = (char*)d_ws;
  ushort* Gn     = (ushort*)ws;                       // 512 KB
  ushort* Wvbf   = (ushort*)(ws + 524288);            // 128 KB
  float*  numden = (float*)(ws + 524288 + 131072);    // 8 KB
  float*  num    = numden;
  float*  den    = numden + BATCH * OUTD;
  float*  Qws    = (float*)(ws + 524288 + 131072 + 8192);  // 1 MB (f32 Q)

  prep1<<<97, 256, 0, stream>>>(query, Wq, bq, Wv, Qws, Wvbf, numden);
  prep2<<<256, 256, 0, stream>>>(Qws, Wk, Gn);
  attn_main<<<BATCH * KCH, 1024, 0, stream>>>(input, Gn, Wvbf, num, den);
  finalize<<<BATCH, 256, 0, stream>>>(num, den, bv, out);
}